// Round 5
// baseline (417.179 us; speedup 1.0000x reference)
//
#include <hip/hip_runtime.h>
#include <hip/hip_bf16.h>

// CorrelationNetwork fused kernels for MI355X (gfx950) — round 5.
// R4 post-mortem: top-5 = harness d_ws poison fills (42.5us fixed). corr
// ~35-40us, pipes: VALU ~20us (integer bf16 pack!), TA ~14us (Ai/Aj re-read
// per tile), LDS ~15us, 3 barriers/tile. R5: independent-wave design —
// stage W2^T + this b's Aj into LDS ONCE, one barrier, then each wave owns
// a 32-row x 128-col strip: h1 frags built in regs from LDS (no At
// round-trip, no global re-reads), full-width w2col -> in-wave epilogue
// (2 shfl, direct store). Packed math (v_pk_*_f32, v_cvt_pk_bf16_f32).

typedef __bf16 bf16x8 __attribute__((ext_vector_type(8)));
typedef float f32x4 __attribute__((ext_vector_type(4)));
typedef float f32x2 __attribute__((ext_vector_type(2)));

#define B_SZ 128
#define N_SZ 64
#define H_SZ 128
#define AJ_STRIDE 132   // 128 + 4 floats pad: row bank-shift 4, 2-way = free

union FragU {
  bf16x8 v;
  __hip_bfloat162 h[4];
};

// ---- setup: blocks 0..2047 prepass (4 bn-rows each), 2048..2111 W2->W2T bf16,
//      block 2112 softmax(mixing_weights)
__global__ __launch_bounds__(256) void setup_kernel(
    const float* __restrict__ af, const float* __restrict__ W1,
    const float* __restrict__ b1, const float* __restrict__ W2,
    const float* __restrict__ mw, float* __restrict__ AiP,
    float* __restrict__ Aj, unsigned short* __restrict__ W2T,
    float* __restrict__ outw)
{
  const int blk = blockIdx.x;
  const int tid = threadIdx.x;

  if (blk < 2048) {
    __shared__ float fl[4 * 64];
    const int bn0 = blk << 2;
    fl[tid] = af[((bn0 + (tid >> 6)) << 7) + (tid & 63)];
    __syncthreads();
    const int h    = tid & 127;
    const int half = tid >> 7;                 // 0 -> Ai, 1 -> Aj
    const float* Wp = W1 + ((half << 6) << 7) + h;
    float acc0 = 0.f, acc1 = 0.f, acc2 = 0.f, acc3 = 0.f;
#pragma unroll
    for (int fq = 0; fq < 16; ++fq) {
      const float w0 = Wp[(fq * 4 + 0) << 7];
      const float w1v = Wp[(fq * 4 + 1) << 7];
      const float w2v = Wp[(fq * 4 + 2) << 7];
      const float w3v = Wp[(fq * 4 + 3) << 7];
      const float4 f0 = *(const float4*)&fl[0 * 64 + (fq << 2)];
      const float4 f1 = *(const float4*)&fl[1 * 64 + (fq << 2)];
      const float4 f2 = *(const float4*)&fl[2 * 64 + (fq << 2)];
      const float4 f3 = *(const float4*)&fl[3 * 64 + (fq << 2)];
      acc0 = fmaf(f0.x, w0, fmaf(f0.y, w1v, fmaf(f0.z, w2v, fmaf(f0.w, w3v, acc0))));
      acc1 = fmaf(f1.x, w0, fmaf(f1.y, w1v, fmaf(f1.z, w2v, fmaf(f1.w, w3v, acc1))));
      acc2 = fmaf(f2.x, w0, fmaf(f2.y, w1v, fmaf(f2.z, w2v, fmaf(f2.w, w3v, acc2))));
      acc3 = fmaf(f3.x, w0, fmaf(f3.y, w1v, fmaf(f3.z, w2v, fmaf(f3.w, w3v, acc3))));
    }
    if (half == 0) {
      const float bb = b1[h];
      AiP[((bn0 + 0) << 7) + h] = acc0 + bb;
      AiP[((bn0 + 1) << 7) + h] = acc1 + bb;
      AiP[((bn0 + 2) << 7) + h] = acc2 + bb;
      AiP[((bn0 + 3) << 7) + h] = acc3 + bb;
    } else {
      Aj[((bn0 + 0) << 7) + h] = acc0;
      Aj[((bn0 + 1) << 7) + h] = acc1;
      Aj[((bn0 + 2) << 7) + h] = acc2;
      Aj[((bn0 + 3) << 7) + h] = acc3;
    }
  } else if (blk < 2112) {
    int idx = ((blk - 2048) << 8) + tid;       // 0..16383
    int k = idx >> 7, n = idx & 127;
    unsigned u = __float_as_uint(W2[idx]);
    u += 0x7fffu + ((u >> 16) & 1u);
    W2T[(n << 7) + k] = (unsigned short)(u >> 16);
  } else {
    if (tid < 64) {
      float v = mw[tid];
      float m = v;
      for (int off = 32; off > 0; off >>= 1) m = fmaxf(m, __shfl_xor(m, off));
      float e = expf(v - m);
      float s = e;
      for (int off = 32; off > 0; off >>= 1) s += __shfl_xor(s, off);
      outw[tid] = e / s;
    }
  }
}

// ---- main kernel: 1024 blocks x 512 thr. block = (b, 8 i's). One stage +
// one barrier, then 8 independent waves x 2 strips each (strip = one i,
// one 32-row j-half, all 128 w2cols).
// MFMA swapped roles: D = W2frag(A) * h1frag(B) -> D[m=w2col][n=h1row].
// A-frag: W2s row (16tm + c), k-chunk ((kt*4+g)^c) [R4-verified, 0 confl].
// B-frag: built in regs: h1[row = jh*32+16tn+c][k = kt*32+8g+j] =
//         relu(AiP[i][k] (global, line-broadcast) + AjS[row][k] (LDS)).
__global__ __launch_bounds__(512, 4) void corr_kernel(
    const float* __restrict__ AiP, const float* __restrict__ Aj,
    const unsigned short* __restrict__ W2T,
    const float* __restrict__ b2, const float* __restrict__ w3,
    const float* __restrict__ b3, float* __restrict__ out)
{
  __shared__ __align__(16) unsigned short W2s[128 * 128];      // 32 KB
  __shared__ __align__(16) float AjS[64 * AJ_STRIDE];          // 33 KB

  const int tid  = threadIdx.x;
  const int lane = tid & 63;
  const int wave = tid >> 6;            // 0..7
  const int c = lane & 15, g = lane >> 4;

  const int blk = blockIdx.x;
  const int b   = blk >> 3;             // 0..127
  const int i0  = (blk & 7) << 3;       // 8 i's for this block

  // ---- stage W2T -> W2s (16B-chunk XOR swizzle), coalesced
  {
    const uint4* src = (const uint4*)W2T;     // 2048 x 16B chunks
#pragma unroll
    for (int it = 0; it < 4; ++it) {
      const int idx = (it << 9) + tid;
      const int n = idx >> 4, e = idx & 15;
      *(uint4*)&W2s[(n << 7) + ((e ^ (n & 15)) << 3)] = src[idx];
    }
  }
  // ---- stage this b's Aj (64 x 128 fp32) -> AjS padded stride 132
  {
    const float4* src = (const float4*)(Aj + ((b << 6) << 7));  // 2048 float4
#pragma unroll
    for (int it = 0; it < 4; ++it) {
      const int idx = (it << 9) + tid;
      const int row = idx >> 5, c4 = idx & 31;
      *(float4*)&AjS[row * AJ_STRIDE + (c4 << 2)] = src[idx];
    }
  }
  __syncthreads();   // the only barrier

  const float bias3 = b3[0];
  const f32x2 zero2 = {0.f, 0.f};

#pragma unroll 1
  for (int si = 0; si < 2; ++si) {
    const int s  = wave + (si << 3);    // strip 0..15
    const int i  = i0 + (s >> 1);
    const int jh = s & 1;               // j-half

    const float* aip = AiP + (((b << 6) + i) << 7) + (g << 3);

    f32x4 acc[8][2];
#pragma unroll
    for (int tm = 0; tm < 8; ++tm) {
      acc[tm][0] = 0.f;
      acc[tm][1] = 0.f;
    }

#pragma unroll
    for (int kt = 0; kt < 4; ++kt) {
      // Ai: 8 floats, same address for all c-lanes (1 line / wave-load)
      const f32x4 ai0 = *(const f32x4*)(aip + (kt << 5));
      const f32x4 ai1 = *(const f32x4*)(aip + (kt << 5) + 4);

      FragU hf[2];
#pragma unroll
      for (int tn = 0; tn < 2; ++tn) {
        const float* ajp =
            &AjS[((jh << 5) + (tn << 4) + c) * AJ_STRIDE + (kt << 5) + (g << 3)];
        const f32x4 aj0 = *(const f32x4*)ajp;
        const f32x4 aj1 = *(const f32x4*)(ajp + 4);
        const f32x2 p0 = __builtin_elementwise_max(ai0.xy + aj0.xy, zero2);
        const f32x2 p1 = __builtin_elementwise_max(ai0.zw + aj0.zw, zero2);
        const f32x2 p2 = __builtin_elementwise_max(ai1.xy + aj1.xy, zero2);
        const f32x2 p3 = __builtin_elementwise_max(ai1.zw + aj1.zw, zero2);
        hf[tn].h[0] = __float22bfloat162_rn(float2{p0.x, p0.y});
        hf[tn].h[1] = __float22bfloat162_rn(float2{p1.x, p1.y});
        hf[tn].h[2] = __float22bfloat162_rn(float2{p2.x, p2.y});
        hf[tn].h[3] = __float22bfloat162_rn(float2{p3.x, p3.y});
      }

      const int es = ((kt << 2) + g) ^ c;   // W2s swizzled chunk
#pragma unroll
      for (int tm = 0; tm < 8; ++tm) {
        const bf16x8 wv =
            *(const bf16x8*)&W2s[(((tm << 4) + c) << 7) + (es << 3)];
        acc[tm][0] = __builtin_amdgcn_mfma_f32_16x16x32_bf16(
            wv, hf[0].v, acc[tm][0], 0, 0, 0);
        acc[tm][1] = __builtin_amdgcn_mfma_f32_16x16x32_bf16(
            wv, hf[1].v, acc[tm][1], 0, 0, 0);
      }
    }

    // ---- epilogue: s = sum_m relu(acc + b2[m]) * w3[m], m = 16tm+4g+p
    f32x2 sp0 = zero2, sp1 = zero2;
#pragma unroll
    for (int tm = 0; tm < 8; ++tm) {
      const f32x4 b2q = *(const f32x4*)(b2 + (tm << 4) + (g << 2));
      const f32x4 w3q = *(const f32x4*)(w3 + (tm << 4) + (g << 2));
      const f32x2 t0a = __builtin_elementwise_max(acc[tm][0].xy + b2q.xy, zero2);
      const f32x2 t0b = __builtin_elementwise_max(acc[tm][0].zw + b2q.zw, zero2);
      const f32x2 t1a = __builtin_elementwise_max(acc[tm][1].xy + b2q.xy, zero2);
      const f32x2 t1b = __builtin_elementwise_max(acc[tm][1].zw + b2q.zw, zero2);
      sp0 = t0a * w3q.xy + sp0;
      sp0 = t0b * w3q.zw + sp0;
      sp1 = t1a * w3q.xy + sp1;
      sp1 = t1b * w3q.zw + sp1;
    }
    float s0 = sp0.x + sp0.y;
    float s1 = sp1.x + sp1.y;
    // sum the 4 g-groups (m bits 2..3): lanes differ in bits 4,5
    s0 += __shfl_xor(s0, 16);
    s0 += __shfl_xor(s0, 32);
    s1 += __shfl_xor(s1, 16);
    s1 += __shfl_xor(s1, 32);

    if (g == 0) {
      const int base = (b << 12) + (i << 6) + (jh << 5);
      out[base + c]      = 1.f / (1.f + __expf(-(s0 + bias3)));
      out[base + 16 + c] = 1.f / (1.f + __expf(-(s1 + bias3)));
    }
  }
}

extern "C" void kernel_launch(void* const* d_in, const int* in_sizes, int n_in,
                              void* d_out, int out_size, void* d_ws,
                              size_t ws_size, hipStream_t stream)
{
  const float* af = (const float*)d_in[0];   // (128,64,128)
  const float* W1 = (const float*)d_in[1];   // (128,128)
  const float* b1 = (const float*)d_in[2];   // (128,)
  const float* W2 = (const float*)d_in[3];   // (128,128)
  const float* b2 = (const float*)d_in[4];   // (128,)
  const float* w3 = (const float*)d_in[5];   // (128,)
  const float* b3 = (const float*)d_in[6];   // (1,)
  const float* mw = (const float*)d_in[7];   // (64,)
  float* out = (float*)d_out;                // 524288 corr + 64 weights

  float* AiP = (float*)d_ws;                           // 4 MB
  float* Aj  = AiP + B_SZ * N_SZ * H_SZ;               // 4 MB
  unsigned short* W2T = (unsigned short*)(Aj + B_SZ * N_SZ * H_SZ);  // 32 KB

  setup_kernel<<<2113, 256, 0, stream>>>(af, W1, b1, W2, mw, AiP, Aj, W2T,
                                         out + B_SZ * N_SZ * N_SZ);
  // 1024 blocks x 8 waves; block = (b, 8 i's); wave = 2 independent strips
  corr_kernel<<<1024, 512, 0, stream>>>(AiP, Aj, W2T, b2, w3, b3, out);
}

// Round 6
// 103.657 us; speedup vs baseline: 4.0246x; 4.0246x over previous
//
#include <hip/hip_runtime.h>
#include <hip/hip_bf16.h>

// CorrelationNetwork fused kernels for MI355X (gfx950) — round 6.
// R5 post-mortem: acc[8][2]=64 VGPR + build temps under launch_bounds(512,4)
// (cap 128) spilled the accumulators to scratch -> 1.1 GB/dispatch HBM
// round-trip, 355us. Law: keep per-lane acc <=32 VGPR at 4 waves/EU.
// R6 = R4 skeleton (known-good ~40us: persistent 512x512, W2s staged once,
// cooperative At tile, swapped-role MFMA, acc[4][2]) + surgical fixes:
//  (1) packed-math build: v_pk_add/max + v_cvt_pk_bf16_f32, 4 passes,
//      each thread emits one 16B chunk (ds_write_b128);
//  (2) 2 barriers/tile instead of 3 (post-epilogue sync orders At reuse);
//  (3) packed epilogue (f32x2).

typedef __bf16 bf16x8 __attribute__((ext_vector_type(8)));
typedef float f32x4 __attribute__((ext_vector_type(4)));
typedef float f32x2 __attribute__((ext_vector_type(2)));

#define B_SZ 128
#define N_SZ 64
#define H_SZ 128

union Frag16 {
  uint4 q;
  __hip_bfloat162 h[4];
};

// ---- setup: blocks 0..2047 prepass (4 bn-rows each), 2048..2111 W2->W2T bf16,
//      block 2112 softmax(mixing_weights)
__global__ __launch_bounds__(256) void setup_kernel(
    const float* __restrict__ af, const float* __restrict__ W1,
    const float* __restrict__ b1, const float* __restrict__ W2,
    const float* __restrict__ mw, float* __restrict__ AiP,
    float* __restrict__ Aj, unsigned short* __restrict__ W2T,
    float* __restrict__ outw)
{
  const int blk = blockIdx.x;
  const int tid = threadIdx.x;

  if (blk < 2048) {
    // prepass: AiP[bn,h] = sum_f f[bn,f]*W1[f,h] + b1[h]; Aj via W1[64+f]
    __shared__ float fl[4 * 64];
    const int bn0 = blk << 2;
    fl[tid] = af[((bn0 + (tid >> 6)) << 7) + (tid & 63)];
    __syncthreads();
    const int h    = tid & 127;
    const int half = tid >> 7;                 // 0 -> Ai, 1 -> Aj
    const float* Wp = W1 + ((half << 6) << 7) + h;
    float acc0 = 0.f, acc1 = 0.f, acc2 = 0.f, acc3 = 0.f;
#pragma unroll
    for (int fq = 0; fq < 16; ++fq) {
      const float w0 = Wp[(fq * 4 + 0) << 7];
      const float w1v = Wp[(fq * 4 + 1) << 7];
      const float w2v = Wp[(fq * 4 + 2) << 7];
      const float w3v = Wp[(fq * 4 + 3) << 7];
      const float4 f0 = *(const float4*)&fl[0 * 64 + (fq << 2)];
      const float4 f1 = *(const float4*)&fl[1 * 64 + (fq << 2)];
      const float4 f2 = *(const float4*)&fl[2 * 64 + (fq << 2)];
      const float4 f3 = *(const float4*)&fl[3 * 64 + (fq << 2)];
      acc0 = fmaf(f0.x, w0, fmaf(f0.y, w1v, fmaf(f0.z, w2v, fmaf(f0.w, w3v, acc0))));
      acc1 = fmaf(f1.x, w0, fmaf(f1.y, w1v, fmaf(f1.z, w2v, fmaf(f1.w, w3v, acc1))));
      acc2 = fmaf(f2.x, w0, fmaf(f2.y, w1v, fmaf(f2.z, w2v, fmaf(f2.w, w3v, acc2))));
      acc3 = fmaf(f3.x, w0, fmaf(f3.y, w1v, fmaf(f3.z, w2v, fmaf(f3.w, w3v, acc3))));
    }
    if (half == 0) {
      const float bb = b1[h];
      AiP[((bn0 + 0) << 7) + h] = acc0 + bb;
      AiP[((bn0 + 1) << 7) + h] = acc1 + bb;
      AiP[((bn0 + 2) << 7) + h] = acc2 + bb;
      AiP[((bn0 + 3) << 7) + h] = acc3 + bb;
    } else {
      Aj[((bn0 + 0) << 7) + h] = acc0;
      Aj[((bn0 + 1) << 7) + h] = acc1;
      Aj[((bn0 + 2) << 7) + h] = acc2;
      Aj[((bn0 + 3) << 7) + h] = acc3;
    }
  } else if (blk < 2112) {
    // W2 (128x128, k-major) -> W2T (n-major) bf16
    int idx = ((blk - 2048) << 8) + tid;       // 0..16383
    int k = idx >> 7, n = idx & 127;
    unsigned u = __float_as_uint(W2[idx]);
    u += 0x7fffu + ((u >> 16) & 1u);
    W2T[(n << 7) + k] = (unsigned short)(u >> 16);
  } else {
    // softmax over 64 mixing weights
    if (tid < 64) {
      float v = mw[tid];
      float m = v;
      for (int off = 32; off > 0; off >>= 1) m = fmaxf(m, __shfl_xor(m, off));
      float e = expf(v - m);
      float s = e;
      for (int off = 32; off > 0; off >>= 1) s += __shfl_xor(s, off);
      outw[tid] = e / s;
    }
  }
}

// ---- main kernel (persistent): 512 blocks x 512 thr, block = (b, 8 ip's).
// Per tile (b, ip): 128 rows r -> i = 2*ip + r/64, j = r%64; full 128 cols.
// Waves: wm = wave&1 (w2col half), wn = wave>>1 (row quarter, 32 rows).
// MFMA swapped roles: D = W2frag(A) * h1frag(B) -> D[m=w2col][n=h1row].
// All frags from swizzled LDS (chunk e' = e ^ (row&15)); W2 staged once.
__global__ __launch_bounds__(512, 4) void corr_kernel(
    const float* __restrict__ AiP, const float* __restrict__ Aj,
    const unsigned short* __restrict__ W2T,
    const float* __restrict__ b2, const float* __restrict__ w3,
    const float* __restrict__ b3, float* __restrict__ out)
{
  __shared__ __align__(16) unsigned short W2s[128 * 128];  // 32 KB
  __shared__ __align__(16) unsigned short At[128 * 128];   // 32 KB
  __shared__ float part[256];                              // [row][wm]

  const int tid  = threadIdx.x;
  const int lane = tid & 63;
  const int wave = tid >> 6;            // 0..7
  const int c = lane & 15, g = lane >> 4;
  const int wm = wave & 1;              // w2col half (64 cols)
  const int wn = wave >> 1;             // row quarter (32 rows)

  const int blk = blockIdx.x;
  const int b   = blk >> 2;             // 0..127
  const int ip0 = (blk & 3) << 3;       // this block's 8 i-pairs

  // ---- stage W2T -> W2s swizzled, once per block (coalesced reads)
  {
    const uint4* src = (const uint4*)W2T;     // 2048 x 16B chunks
#pragma unroll
    for (int it = 0; it < 4; ++it) {
      const int idx = (it << 9) + tid;        // 0..2047
      const int n = idx >> 4, e = idx & 15;
      const uint4 v = src[idx];
      *(uint4*)&W2s[(n << 7) + ((e ^ (n & 15)) << 3)] = v;
    }
  }

  // per-wave b2/w3 slices: w2col = 64*wm + 16*tm + 4*g + p
  f32x4 b2v[4], w3v[4];
#pragma unroll
  for (int tm = 0; tm < 4; ++tm) {
    b2v[tm] = *(const f32x4*)(b2 + (wm << 6) + (tm << 4) + (g << 2));
    w3v[tm] = *(const f32x4*)(w3 + (wm << 6) + (tm << 4) + (g << 2));
  }
  const float bias3 = b3[0];
  const f32x4 zero4 = {0.f, 0.f, 0.f, 0.f};
  const f32x2 zero2 = {0.f, 0.f};

  const float* AjB = Aj + ((b << 6) << 7);    // this b's 64 Aj rows

  // build-phase thread mapping: thread -> (row rr, 16B chunk kq8)
  const int kq8 = tid & 15;                   // chunk = 8 floats -> 8 bf16
  const int rr  = tid >> 4;                   // 0..31 (row within pass)

  for (int t = 0; t < 8; ++t) {
    const int i0 = (ip0 + t) << 1;
    const float* AiB = AiP + (((b << 6) + i0) << 7);

    // ---- build h1 tile -> At (bf16, swizzled): 4 passes, b128 writes.
    // Ordering vs previous tile: the post-epilogue barrier of iter t-1
    // guarantees all At reads and part reads of t-1 are complete.
#pragma unroll
    for (int pass = 0; pass < 4; ++pass) {
      const int r = (pass << 5) + rr;
      const float* arow = AiB + ((r >> 6) << 7) + (kq8 << 3);
      const float* jrow = AjB + ((r & 63) << 7) + (kq8 << 3);
      const f32x4 a0 = *(const f32x4*)arow;
      const f32x4 a1 = *(const f32x4*)(arow + 4);
      const f32x4 j0 = *(const f32x4*)jrow;
      const f32x4 j1 = *(const f32x4*)(jrow + 4);
      const f32x4 s0 = __builtin_elementwise_max(a0 + j0, zero4);
      const f32x4 s1 = __builtin_elementwise_max(a1 + j1, zero4);
      Frag16 u;
      u.h[0] = __float22bfloat162_rn(float2{s0.x, s0.y});
      u.h[1] = __float22bfloat162_rn(float2{s0.z, s0.w});
      u.h[2] = __float22bfloat162_rn(float2{s1.x, s1.y});
      u.h[3] = __float22bfloat162_rn(float2{s1.z, s1.w});
      *(uint4*)&At[(r << 7) + ((kq8 ^ (r & 15)) << 3)] = u.q;
    }

    __syncthreads();

    // ---- MFMA: acc init = b2 (D = A*B + C)
    f32x4 acc[4][2];
#pragma unroll
    for (int tm = 0; tm < 4; ++tm) {
      acc[tm][0] = b2v[tm];
      acc[tm][1] = b2v[tm];
    }

#pragma unroll
    for (int kt = 0; kt < 4; ++kt) {
      const int es = ((kt << 2) + g) ^ c;     // swizzled chunk (row low4 == c)
      bf16x8 wv[4], hv[2];
#pragma unroll
      for (int tm = 0; tm < 4; ++tm)
        wv[tm] = *(const bf16x8*)&W2s[(((wm << 6) + (tm << 4) + c) << 7) + (es << 3)];
#pragma unroll
      for (int tn = 0; tn < 2; ++tn)
        hv[tn] = *(const bf16x8*)&At[(((wn << 5) + (tn << 4) + c) << 7) + (es << 3)];
#pragma unroll
      for (int tm = 0; tm < 4; ++tm)
#pragma unroll
        for (int tn = 0; tn < 2; ++tn)
          acc[tm][tn] = __builtin_amdgcn_mfma_f32_16x16x32_bf16(
              wv[tm], hv[tn], acc[tm][tn], 0, 0, 0);
    }

    // ---- epilogue: in-lane over (tm,p) packed, shfl over g, LDS combine wm
    f32x2 sp0 = zero2, sp1 = zero2;
#pragma unroll
    for (int tm = 0; tm < 4; ++tm) {
      const f32x2 w3a = w3v[tm].xy, w3b = w3v[tm].zw;
      sp0 = __builtin_elementwise_max(acc[tm][0].xy, zero2) * w3a + sp0;
      sp0 = __builtin_elementwise_max(acc[tm][0].zw, zero2) * w3b + sp0;
      sp1 = __builtin_elementwise_max(acc[tm][1].xy, zero2) * w3a + sp1;
      sp1 = __builtin_elementwise_max(acc[tm][1].zw, zero2) * w3b + sp1;
    }
    float s0 = sp0.x + sp0.y;
    float s1 = sp1.x + sp1.y;
    s0 += __shfl_xor(s0, 16);
    s0 += __shfl_xor(s0, 32);
    s1 += __shfl_xor(s1, 16);
    s1 += __shfl_xor(s1, 32);
    if (g == 0) {                              // 16 lanes, conflict-free
      part[(((wn << 5) + c) << 1) + wm]      = s0;
      part[(((wn << 5) + 16 + c) << 1) + wm] = s1;
    }

    __syncthreads();

    if (tid < 128) {
      const float2 pp = *(const float2*)&part[tid << 1];
      const float v = pp.x + pp.y + bias3;
      out[(b << 12) + (i0 << 6) + tid] = 1.f / (1.f + __expf(-v));
    }
  }
}

extern "C" void kernel_launch(void* const* d_in, const int* in_sizes, int n_in,
                              void* d_out, int out_size, void* d_ws,
                              size_t ws_size, hipStream_t stream)
{
  const float* af = (const float*)d_in[0];   // (128,64,128)
  const float* W1 = (const float*)d_in[1];   // (128,128)
  const float* b1 = (const float*)d_in[2];   // (128,)
  const float* W2 = (const float*)d_in[3];   // (128,128)
  const float* b2 = (const float*)d_in[4];   // (128,)
  const float* w3 = (const float*)d_in[5];   // (128,)
  const float* b3 = (const float*)d_in[6];   // (1,)
  const float* mw = (const float*)d_in[7];   // (64,)
  float* out = (float*)d_out;                // 524288 corr + 64 weights

  float* AiP = (float*)d_ws;                           // 4 MB
  float* Aj  = AiP + B_SZ * N_SZ * H_SZ;               // 4 MB
  unsigned short* W2T = (unsigned short*)(Aj + B_SZ * N_SZ * H_SZ);  // 32 KB

  setup_kernel<<<2113, 256, 0, stream>>>(af, W1, b1, W2, mw, AiP, Aj, W2T,
                                         out + B_SZ * N_SZ * N_SZ);
  // persistent: 512 blocks (2/CU), each owns 8 (b, i-pair) tiles
  corr_kernel<<<512, 512, 0, stream>>>(AiP, Aj, W2T, b2, w3, b3, out);
}